// Round 3
// baseline (543.401 us; speedup 1.0000x reference)
//
#include <hip/hip_runtime.h>

// Attention_884763263569 on gfx950 — v5.
// x:[65536,3,512] f32, Wk/Wv:[32,512], Wq:[32,1536], Wfc:[10,32], bfc:[10] -> out [65536,10] f32.
//
// Folding: out = sum_t a_t * (Wfc@Wv @ x_t) + bfc  ->  Wvf = Wfc@Wv [10,512].
// Combined per-t logical weight rows (80, fp16): 0..31 Wk | 32..63 Wq slice t | 64..73 Wvf | 74..79 zero.
// v5 vs v4: the x HBM stream is made CONTIGUOUS. All prior versions read 16 scattered
// 64-128B segments per wave instruction (sample rows 6KB apart) -> ~27% HBM efficiency.
// Now: 1-wave blocks (64 thr) own 16 samples; x staged via global_load_lds in 1KB-per-row
// windows (each glds = one contiguous aligned 1KB = 16 sequential lines), 16KB windows,
// double-buffered (32KB LDS -> 5 blocks/CU). A-fragments read from LDS with an XOR swizzle
// (slot ^ (row&7)) applied on BOTH the per-lane global source (within the same 1KB window,
// so contiguity is preserved) and the ds_read address -> 2-way bank access (free) instead
// of 16-way. Single-wave __syncthreads (~free) gives stage(w+1) || compute(w) overlap.

typedef __attribute__((ext_vector_type(4))) float  f32x4;
typedef __attribute__((ext_vector_type(8))) _Float16 h16x8;

#define T_VIEWS 3
#define D_DIM   512
#define ROW_F   (T_VIEWS * D_DIM)   // 1536 floats per sample row
#define P_DIM   32
#define C_DIM   10
#define NROWS   80                  // padded logical rows per t
#define NT      5                   // n-tiles of 16
#define KC      16                  // k-chunks of 32 per t
#define M_SAMP  16                  // samples per block (one wave, one M-tile)
#define NWIN    6                   // 1KB windows per row (6KB row)
#define WIN_F   256                 // floats per row per window
#define JW      8                   // k-steps per window
#define WIN_BYTES (M_SAMP * 1024)   // 16KB per window buffer

// ---------------- Kernel A: build fragment-ordered fp16 weights in d_ws ----------------
// Logical (t, j, d) -> frag addr (((t*KC+kc)*NT+n)*64 + quad*16+col)*8 + jj
// K-permutation within a 32-chunk: r = d&31 -> quad=(r>>2)&3, jj=((r>>4)<<2)|(r&3),
// i.e. element jj of quad q is k = (jj<4 ? 4q+jj : 16+4q+jj-4). Matches the A-side reads.
__global__ void build_weights(const float* __restrict__ Wk,
                              const float* __restrict__ Wv,
                              const float* __restrict__ Wq,
                              const float* __restrict__ Wfc,
                              _Float16* __restrict__ Wf) {
    const int row = blockIdx.x;          // 0 .. 3*80-1
    const int t   = row / NROWS;
    const int j   = row % NROWS;
    const int d   = threadIdx.x;         // 0..511
    float val;
    if (j < 32) {
        val = Wk[j * D_DIM + d];
    } else if (j < 64) {
        const int p = j - 32;
        val = Wq[p * (T_VIEWS * D_DIM) + t * D_DIM + d];
    } else if (j < 64 + C_DIM) {
        const int i = j - 64;
        float s = 0.f;
        #pragma unroll
        for (int p = 0; p < P_DIM; ++p)
            s += Wfc[i * P_DIM + p] * Wv[p * D_DIM + d];
        val = s;
    } else {
        val = 0.f;                        // pad rows (d_ws is poisoned -> must zero)
    }
    const int n = j >> 4, coln = j & 15;
    const int kc = d >> 5, r = d & 31;
    const int quad = (r >> 2) & 3;                 // K-permuted quad
    const int jj   = ((r >> 4) << 2) | (r & 3);    // K-permuted element index
    const size_t addr = (size_t)((((t * KC + kc) * NT + n) * 64) + quad * 16 + coln) * 8 + jj;
    Wf[addr] = (_Float16)val;
}

// ---------------- Main fused kernel ----------------
__global__ __launch_bounds__(64, 2) void attn_fused(
        const float* __restrict__ x,
        const _Float16* __restrict__ Wf,
        const float* __restrict__ bfc,
        float* __restrict__ out) {
    __shared__ char lds[2 * WIN_BYTES];   // 32 KB double-buffered x-window store

    const int lane = threadIdx.x;         // blockDim = 64: one wave
    const int col  = lane & 15;           // MFMA: A-row m (sample) / B-col n / C-col
    const int quad = lane >> 4;           // MFMA: k-group / C row-group
    const int row_base = blockIdx.x * M_SAMP;

    // accumulators: k per-t (2 halves), q SHARED across t (MFMA C-chain), yv per-t
    f32x4 acc_k[3][2];
    f32x4 acc_q[2];
    f32x4 acc_y[3];
    #pragma unroll
    for (int t = 0; t < 3; ++t) {
        acc_k[t][0] = (f32x4)0.f;
        acc_k[t][1] = (f32x4)0.f;
        acc_y[t]    = (f32x4)0.f;
    }
    acc_q[0] = (f32x4)0.f;
    acc_q[1] = (f32x4)0.f;

    // Stage window w into buf: glds i stages row i's contiguous 1KB window.
    // Per-lane global slot = lane ^ (i&7) (stays within the SAME 1KB window -> the wave
    // instruction still covers exactly one aligned contiguous 1KB). LDS ends up holding
    // row i's slots in XOR(i&7)-permuted order; reads below apply the same XOR.
    auto STAGE = [&](int w, char* buf) {
        #pragma unroll
        for (int i = 0; i < M_SAMP; ++i) {
            const float* src = x + (size_t)(row_base + i) * ROW_F + w * WIN_F
                                 + ((lane ^ (i & 7)) << 2);
            __builtin_amdgcn_global_load_lds(
                (const __attribute__((address_space(1))) void*)src,
                (__attribute__((address_space(3))) void*)(buf + i * 1024),
                16, 0, 0);
        }
    };

    STAGE(0, lds);

    #pragma unroll
    for (int w = 0; w < NWIN; ++w) {
        __syncthreads();                          // vmcnt(0) drain: window w landed; prev reads done
        if (w + 1 < NWIN)
            STAGE(w + 1, lds + ((w + 1) & 1) * WIN_BYTES);   // overlaps compute below
        const char* buf = lds + (w & 1) * WIN_BYTES;
        const int t = w >> 1;                     // 2 windows per view (512 floats)
        const _Float16* wbase = Wf + (size_t)(w * JW) * NT * 512 + lane * 8;

        #pragma unroll
        for (int j = 0; j < JW; ++j) {
            h16x8 b[NT];
            #pragma unroll
            for (int n = 0; n < NT; ++n)
                b[n] = *(const h16x8*)(wbase + (size_t)(j * NT + n) * 512);
            // A-fragment: lane (col,quad) holds k = {4q..4q+3} U {16+4q..16+4q+3} of step j.
            // LDS slots (j*8+q) and (j*8+4+q), XOR'd by (col&7): 2-way banks (free).
            const f32x4 x0 = *(const f32x4*)(buf + col * 1024 + (((j * 8 + quad)     ^ (col & 7)) << 4));
            const f32x4 x1 = *(const f32x4*)(buf + col * 1024 + (((j * 8 + 4 + quad) ^ (col & 7)) << 4));
            h16x8 a;
            #pragma unroll
            for (int i = 0; i < 4; ++i) {
                a[i]     = (_Float16)x0[i];
                a[i + 4] = (_Float16)x1[i];
            }
            acc_k[t][0] = __builtin_amdgcn_mfma_f32_16x16x32_f16(a, b[0], acc_k[t][0], 0, 0, 0);
            acc_k[t][1] = __builtin_amdgcn_mfma_f32_16x16x32_f16(a, b[1], acc_k[t][1], 0, 0, 0);
            acc_q[0]    = __builtin_amdgcn_mfma_f32_16x16x32_f16(a, b[2], acc_q[0],    0, 0, 0);
            acc_q[1]    = __builtin_amdgcn_mfma_f32_16x16x32_f16(a, b[3], acc_q[1],    0, 0, 0);
            acc_y[t]    = __builtin_amdgcn_mfma_f32_16x16x32_f16(a, b[4], acc_y[t],    0, 0, 0);
        }
    }

    // ---------------- Epilogue (registers + shfl only) ----------------
    // C layout: element r holds sample row (quad*4 + r), column (n*16 + col).
    const float bias = (col < C_DIM) ? bfc[col] : 0.f;

    float outv[4];
    #pragma unroll
    for (int r = 0; r < 4; ++r) {
        const float qa = acc_q[0][r];     // q[sample][p=col]
        const float qb = acc_q[1][r];     // q[sample][p=16+col]
        float s0 = qa * acc_k[0][0][r] + qb * acc_k[0][1][r];
        float s1 = qa * acc_k[1][0][r] + qb * acc_k[1][1][r];
        float s2 = qa * acc_k[2][0][r] + qb * acc_k[2][1][r];
        #pragma unroll
        for (int msk = 1; msk <= 8; msk <<= 1) {
            s0 += __shfl_xor(s0, msk, 64);
            s1 += __shfl_xor(s1, msk, 64);
            s2 += __shfl_xor(s2, msk, 64);
        }
        const float mx = fmaxf(s0, fmaxf(s1, s2));
        const float e0 = __expf(s0 - mx);
        const float e1 = __expf(s1 - mx);
        const float e2 = __expf(s2 - mx);
        const float inv = 1.f / (e0 + e1 + e2);
        outv[r] = (e0 * acc_y[0][r] + e1 * acc_y[1][r] + e2 * acc_y[2][r]) * inv + bias;
    }
    if (col < C_DIM) {
        const int b0 = row_base + quad * 4;
        #pragma unroll
        for (int r = 0; r < 4; ++r)
            out[(size_t)(b0 + r) * C_DIM + col] = outv[r];
    }
}

extern "C" void kernel_launch(void* const* d_in, const int* in_sizes, int n_in,
                              void* d_out, int out_size, void* d_ws, size_t ws_size,
                              hipStream_t stream) {
    const float* x   = (const float*)d_in[0];
    const float* Wk  = (const float*)d_in[1];
    const float* Wv  = (const float*)d_in[2];
    const float* Wq  = (const float*)d_in[3];
    const float* Wfc = (const float*)d_in[4];
    const float* bfc = (const float*)d_in[5];
    _Float16* Wf = (_Float16*)d_ws;       // 3*80*512 halfs = 240 KB, fragment-ordered

    hipLaunchKernelGGL(build_weights, dim3(T_VIEWS * NROWS), dim3(D_DIM), 0, stream,
                       Wk, Wv, Wq, Wfc, Wf);

    const int B_TOTAL = in_sizes[0] / (T_VIEWS * D_DIM);      // 65536
    const int blocks = B_TOTAL / M_SAMP;                      // 4096 one-wave blocks
    hipLaunchKernelGGL(attn_fused, dim3(blocks), dim3(64), 0, stream,
                       x, Wf, bfc, (float*)d_out);
}

// Round 4
// 524.061 us; speedup vs baseline: 1.0369x; 1.0369x over previous
//
#include <hip/hip_runtime.h>

// Attention_884763263569 on gfx950 — v6.
// x:[65536,3,512] f32, Wk/Wv:[32,512], Wq:[32,1536], Wfc:[10,32], bfc:[10] -> out [65536,10] f32.
//
// Folding: out = sum_t a_t * (Wfc@Wv @ x_t) + bfc  ->  Wvf = Wfc@Wv [10,512].
// Combined per-t logical weight rows (80, fp16): 0..31 Wk | 32..63 Wq slice t | 64..73 Wvf | 74..79 zero.
// v6 vs v4:
//  * FULL UNROLL of the 12-super-chunk loop: acc indices become compile-time (rule #20 —
//    v4's runtime t risked scratch-allocated accumulators), guards/parity fold away.
//  * Counted-vmcnt pipeline (T3/T4): per chunk, end with s_waitcnt vmcnt(8) + sched_barrier(0)
//    + raw s_barrier. Retires exactly {x(u+1), Wf-glds(u+1)}; the 8 x-loads of chunk u+2 stay
//    IN FLIGHT across the barrier (no drain-to-0 like __syncthreads).
//  * x register-prefetch 2 chunks ahead (2x8 f32x4, consume-then-overwrite): 13-21 KB of VMEM
//    in flight per wave during compute -> DRAM queue stays deep instead of tight load->cvt->mfma.
//  * Keeps v4's Wf LDS double-buffer (20KB chunks), v3's K-permuted full-line x loads, reg epilogue.

typedef __attribute__((ext_vector_type(4))) float  f32x4;
typedef __attribute__((ext_vector_type(8))) _Float16 h16x8;

#define T_VIEWS 3
#define D_DIM   512
#define P_DIM   32
#define C_DIM   10
#define NROWS   80          // padded logical rows per t
#define NT      5           // n-tiles of 16
#define KC      16          // k-chunks of 32 per t
#define NSTEPS  48          // T_VIEWS*KC
#define JPER    4           // k-steps per super-chunk
#define NSUPER  (NSTEPS/JPER)            // 12
#define STEP_B  (NT*1024)                // 5120 B of fragments per k-step
#define CHUNK_B (JPER*STEP_B)            // 20480 B per super-chunk
#define WAVES_PER_BLOCK 4
#define SAMPLES_PER_BLOCK (16 * WAVES_PER_BLOCK)   // 64

// ---------------- Kernel A: build fragment-ordered fp16 weights in d_ws ----------------
// Logical (t, j, d) -> frag addr (((t*KC+kc)*NT+n)*64 + quad*16+col)*8 + jj
// K-permutation within a 32-chunk: r = d&31 -> quad=(r>>2)&3, jj=((r>>4)<<2)|(r&3),
// i.e. element jj of quad q is k = (jj<4 ? 4q+jj : 16+4q+jj-4). Matches the A-side loads.
__global__ void build_weights(const float* __restrict__ Wk,
                              const float* __restrict__ Wv,
                              const float* __restrict__ Wq,
                              const float* __restrict__ Wfc,
                              _Float16* __restrict__ Wf) {
    const int row = blockIdx.x;          // 0 .. 3*80-1
    const int t   = row / NROWS;
    const int j   = row % NROWS;
    const int d   = threadIdx.x;         // 0..511
    float val;
    if (j < 32) {
        val = Wk[j * D_DIM + d];
    } else if (j < 64) {
        const int p = j - 32;
        val = Wq[p * (T_VIEWS * D_DIM) + t * D_DIM + d];
    } else if (j < 64 + C_DIM) {
        const int i = j - 64;
        float s = 0.f;
        #pragma unroll
        for (int p = 0; p < P_DIM; ++p)
            s += Wfc[i * P_DIM + p] * Wv[p * D_DIM + d];
        val = s;
    } else {
        val = 0.f;                        // pad rows (d_ws is poisoned -> must zero)
    }
    const int n = j >> 4, coln = j & 15;
    const int kc = d >> 5, r = d & 31;
    const int quad = (r >> 2) & 3;                 // K-permuted quad
    const int jj   = ((r >> 4) << 2) | (r & 3);    // K-permuted element index
    const size_t addr = (size_t)((((t * KC + kc) * NT + n) * 64) + quad * 16 + coln) * 8 + jj;
    Wf[addr] = (_Float16)val;
}

// ---------------- Main fused kernel ----------------
__global__ __launch_bounds__(256, 3) void attn_fused(
        const float* __restrict__ x,
        const _Float16* __restrict__ Wf,
        const float* __restrict__ bfc,
        float* __restrict__ out) {
    __shared__ char lds[2 * CHUNK_B];    // 40 KB double-buffered Wf fragment store

    const int lane = threadIdx.x & 63;
    const int wave = threadIdx.x >> 6;
    const int col  = lane & 15;          // MFMA: A-row m (sample) / B-col n / C-col
    const int quad = lane >> 4;          // MFMA: k-group / C row-group
    const int row_base = blockIdx.x * SAMPLES_PER_BLOCK + wave * 16;

    // accumulators: k per-t (2 halves), q SHARED across t (MFMA C-chain), yv per-t
    f32x4 acc_k[3][2];
    f32x4 acc_q[2];
    f32x4 acc_y[3];
    #pragma unroll
    for (int t = 0; t < 3; ++t) {
        acc_k[t][0] = (f32x4)0.f;
        acc_k[t][1] = (f32x4)0.f;
        acc_y[t]    = (f32x4)0.f;
    }
    acc_q[0] = (f32x4)0.f;
    acc_q[1] = (f32x4)0.f;

    // A-operand: lane (col,quad) -> sample row = col; K-permuted:
    //   x0 @ +quad*4 floats (k = 4q..4q+3), x1 @ +64B further (k = 16+4q..16+4q+3).
    // Each x-load instruction covers 16 full 64B lines, each line touched exactly once.
    const float* xbase = x + (size_t)(row_base + col) * (T_VIEWS * D_DIM) + quad * 4;
    const char*  wfg   = (const char*)Wf + lane * 16;   // per-lane global src for Wf staging

    f32x4 xA[2 * JPER];   // x regs, even chunks
    f32x4 xB[2 * JPER];   // x regs, odd chunks

    // stage Wf chunk u into lds[u&1] (4 waves x 5 glds of 1KB)
    auto GLDS = [&](int u) {
        #pragma unroll
        for (int i = 0; i < 5; ++i) {
            const int idx = wave * 5 + i;
            __builtin_amdgcn_global_load_lds(
                (const __attribute__((address_space(1))) void*)(wfg + (size_t)u * CHUNK_B + idx * 1024),
                (__attribute__((address_space(3))) void*)(lds + (u & 1) * CHUNK_B + idx * 1024),
                16, 0, 0);
        }
    };
    // issue the 8 x-loads of chunk u into xr (u compile-time after unroll)
    auto LOADX = [&](int u, f32x4* xr) {
        #pragma unroll
        for (int j = 0; j < JPER; ++j) {
            const int s = u * JPER + j, t = s >> 4, kc = s & 15;
            const float* xp = xbase + t * D_DIM + kc * 32;
            xr[2 * j]     = __builtin_nontemporal_load((const f32x4*)xp);
            xr[2 * j + 1] = __builtin_nontemporal_load((const f32x4*)(xp + 16));
        }
    };
    // compute chunk u from lds[u&1] + xr
    auto BODY = [&](int u, const f32x4* xr) {
        const char* buf = lds + (u & 1) * CHUNK_B;
        #pragma unroll
        for (int j = 0; j < JPER; ++j) {
            const int s = u * JPER + j, t = s >> 4;   // compile-time post-unroll
            h16x8 b[NT];
            #pragma unroll
            for (int n = 0; n < NT; ++n)
                b[n] = *(const h16x8*)(buf + j * STEP_B + n * 1024 + lane * 16);
            h16x8 a;
            #pragma unroll
            for (int i = 0; i < 4; ++i) {
                a[i]     = (_Float16)xr[2 * j][i];
                a[i + 4] = (_Float16)xr[2 * j + 1][i];
            }
            acc_k[t][0] = __builtin_amdgcn_mfma_f32_16x16x32_f16(a, b[0], acc_k[t][0], 0, 0, 0);
            acc_k[t][1] = __builtin_amdgcn_mfma_f32_16x16x32_f16(a, b[1], acc_k[t][1], 0, 0, 0);
            acc_q[0]    = __builtin_amdgcn_mfma_f32_16x16x32_f16(a, b[2], acc_q[0],    0, 0, 0);
            acc_q[1]    = __builtin_amdgcn_mfma_f32_16x16x32_f16(a, b[3], acc_q[1],    0, 0, 0);
            acc_y[t]    = __builtin_amdgcn_mfma_f32_16x16x32_f16(a, b[4], acc_y[t],    0, 0, 0);
        }
    };

    // ---- prologue: glds(0) + x(0) + x(1) in flight; retire only glds(0) (vmcnt 16 = x0+x1) ----
    GLDS(0);
    LOADX(0, xA);
    LOADX(1, xB);
    asm volatile("s_waitcnt vmcnt(16)" ::: "memory");
    __builtin_amdgcn_sched_barrier(0);
    __builtin_amdgcn_s_barrier();

    // ---- main loop, fully unrolled: counted vmcnt keeps x(u+2) in flight across barriers ----
    #pragma unroll
    for (int u = 0; u < NSUPER; ++u) {
        f32x4* xcur = (u & 1) ? xB : xA;
        if (u + 1 < NSUPER) GLDS(u + 1);          // into lds[(u+1)&1]
        BODY(u, xcur);                            // consume x(u); compiler auto-waits counted
        if (u + 2 < NSUPER) LOADX(u + 2, xcur);   // overwrite AFTER consumption (same parity)
        if (u + 1 < NSUPER) {
            if (u + 2 < NSUPER) {
                // queue (oldest->newest): x(u+1):8, glds(u+1):5, x(u+2):8 -> retire first 13
                asm volatile("s_waitcnt vmcnt(8)" ::: "memory");
            } else {
                // tail (u = NSUPER-2): nothing issued after glds(u+1) -> full drain is cheap
                asm volatile("s_waitcnt vmcnt(0)" ::: "memory");
            }
            __builtin_amdgcn_sched_barrier(0);
            __builtin_amdgcn_s_barrier();
        }
    }

    // ---------------- Epilogue (registers + shfl only) ----------------
    // C layout: element r holds sample row (quad*4 + r), column (n*16 + col).
    const float bias = (col < C_DIM) ? bfc[col] : 0.f;

    float outv[4];
    #pragma unroll
    for (int r = 0; r < 4; ++r) {
        const float qa = acc_q[0][r];     // q[sample][p=col]
        const float qb = acc_q[1][r];     // q[sample][p=16+col]
        float s0 = qa * acc_k[0][0][r] + qb * acc_k[0][1][r];
        float s1 = qa * acc_k[1][0][r] + qb * acc_k[1][1][r];
        float s2 = qa * acc_k[2][0][r] + qb * acc_k[2][1][r];
        #pragma unroll
        for (int msk = 1; msk <= 8; msk <<= 1) {
            s0 += __shfl_xor(s0, msk, 64);
            s1 += __shfl_xor(s1, msk, 64);
            s2 += __shfl_xor(s2, msk, 64);
        }
        const float mx = fmaxf(s0, fmaxf(s1, s2));
        const float e0 = __expf(s0 - mx);
        const float e1 = __expf(s1 - mx);
        const float e2 = __expf(s2 - mx);
        const float inv = 1.f / (e0 + e1 + e2);
        outv[r] = (e0 * acc_y[0][r] + e1 * acc_y[1][r] + e2 * acc_y[2][r]) * inv + bias;
    }
    if (col < C_DIM) {
        const int b0 = row_base + quad * 4;
        #pragma unroll
        for (int r = 0; r < 4; ++r)
            out[(size_t)(b0 + r) * C_DIM + col] = outv[r];
    }
}

extern "C" void kernel_launch(void* const* d_in, const int* in_sizes, int n_in,
                              void* d_out, int out_size, void* d_ws, size_t ws_size,
                              hipStream_t stream) {
    const float* x   = (const float*)d_in[0];
    const float* Wk  = (const float*)d_in[1];
    const float* Wv  = (const float*)d_in[2];
    const float* Wq  = (const float*)d_in[3];
    const float* Wfc = (const float*)d_in[4];
    const float* bfc = (const float*)d_in[5];
    _Float16* Wf = (_Float16*)d_ws;       // 3*80*512 halfs = 240 KB, fragment-ordered

    hipLaunchKernelGGL(build_weights, dim3(T_VIEWS * NROWS), dim3(D_DIM), 0, stream,
                       Wk, Wv, Wq, Wfc, Wf);

    const int B_TOTAL = in_sizes[0] / (T_VIEWS * D_DIM);      // 65536
    const int blocks = B_TOTAL / SAMPLES_PER_BLOCK;           // 1024
    hipLaunchKernelGGL(attn_fused, dim3(blocks), dim3(256), 0, stream,
                       x, Wf, bfc, (float*)d_out);
}